// Round 2
// baseline (235.490 us; speedup 1.0000x reference)
//
#include <hip/hip_runtime.h>
#include <math.h>

#define NLAYERS 2
#define HID 128
#define FFND 256
#define NH 4
#define SEQL 2048
#define HD 32
#define HDV 64
#define VD 256
#define NBATCH 2
#define MROWS (NBATCH*SEQL)   // 4096
#define NCAT 768              // Q(128) | K(128) | V(256) | G(256)
#define NCHUNK 32             // SEQL / 64

// ---------------------------------------------------------------------------
// Pack per-head weights into one (HID x 768) matrix per layer:
// cols [0,128): Q  [128,256): K  [256,512): V  [512,768): G
// ---------------------------------------------------------------------------
__global__ __launch_bounds__(256) void pack_w_kernel(
    const float* __restrict__ WQ, const float* __restrict__ WK,
    const float* __restrict__ WV, const float* __restrict__ WG,
    float* __restrict__ Wcat)
{
  int idx = blockIdx.x * 256 + threadIdx.x;
  if (idx >= NLAYERS * HID * NCAT) return;
  int l = idx / (HID * NCAT);
  int r = idx - l * (HID * NCAT);
  int k = r / NCAT;
  int n = r - k * NCAT;
  float v;
  if (n < 128)      { int h = n >> 5, e = n & 31;          v = WQ[(((l*NH+h)*HID)+k)*HD  + e]; }
  else if (n < 256) { int m = n-128; int h = m>>5, e = m&31; v = WK[(((l*NH+h)*HID)+k)*HD  + e]; }
  else if (n < 512) { int m = n-256; int h = m>>6, e = m&63; v = WV[(((l*NH+h)*HID)+k)*HDV + e]; }
  else              { v = WG[(l*HID + k)*VD + (n-512)]; }
  Wcat[idx] = v;
}

// ---------------------------------------------------------------------------
// xPos tables: sinQ/cosQ (scaled) and sinK/cosK (inverse-scaled), SEQ x 16
// ---------------------------------------------------------------------------
__global__ __launch_bounds__(256) void xpos_tables_kernel(float* __restrict__ tabs)
{
  int idx = blockIdx.x * 256 + threadIdx.x;   // s*16 + i
  if (idx >= SEQL * 16) return;
  int s = idx >> 4, i = idx & 15;
  float inv_freq = powf(10000.f, -(float)i * (1.f/16.f));
  float ang = (float)s * inv_freq;
  float sv  = ((float)(2*i) + 0.4f*32.f) / (1.4f*32.f);
  float sc  = powf(sv, (float)s * (1.f/512.f));
  float sn = sinf(ang), cs = cosf(ang);
  tabs[idx]          = sn * sc;   // sinQ
  tabs[32768 + idx]  = cs * sc;   // cosQ
  tabs[65536 + idx]  = sn / sc;   // sinK
  tabs[98304 + idx]  = cs / sc;   // cosK
}

// ---------------------------------------------------------------------------
// LayerNorm over rows of 128; one wave per row, 4 rows per block.
// ---------------------------------------------------------------------------
__global__ __launch_bounds__(256) void ln_rows_kernel(
    const float* __restrict__ X, const float* __restrict__ g,
    const float* __restrict__ b, float* __restrict__ O)
{
  int wid = threadIdx.x >> 6, lane = threadIdx.x & 63;
  int row = blockIdx.x * 4 + wid;
  const float* x = X + (size_t)row * HID;
  float v0 = x[lane], v1 = x[lane + 64];
  float s = v0 + v1;
  #pragma unroll
  for (int o = 32; o; o >>= 1) s += __shfl_xor(s, o);
  float mu = s * (1.f/128.f);
  float d0 = v0 - mu, d1 = v1 - mu;
  float q = d0*d0 + d1*d1;
  #pragma unroll
  for (int o = 32; o; o >>= 1) q += __shfl_xor(q, o);
  float rs = rsqrtf(q * (1.f/128.f) + 1e-5f);
  O[(size_t)row*HID + lane]      = d0 * rs * g[lane]      + b[lane];
  O[(size_t)row*HID + lane + 64] = d1 * rs * g[lane + 64] + b[lane + 64];
}

// ---------------------------------------------------------------------------
// Generic fp32 GEMM: C[M,N] = A[M,KTOT] @ B[KTOT,N] (+bias)(gelu)(+resid)(xpos)
// 64x64 tile, BK=64, 256 threads, 4x4 microtile.
// A staged transposed [k][row] with k-dependent row-XOR swizzle (2-way banks).
// ---------------------------------------------------------------------------
template<int KTOT, bool BIAS, bool RESID, bool GELU, bool XPOS>
__global__ __launch_bounds__(256) void gemm64(
    const float* __restrict__ A, const float* __restrict__ Bw,
    const float* __restrict__ bias, const float* __restrict__ Rsd,
    const float* __restrict__ tabs, float* __restrict__ C, int N)
{
  __shared__ float As[64][68];
  __shared__ float Bs[64][68];
  int tid = threadIdx.x;
  int tx = tid & 15, ty = tid >> 4;
  int rb = blockIdx.x * 64, nb = blockIdx.y * 64;

  float acc[4][4];
  #pragma unroll
  for (int i=0;i<4;i++)
    #pragma unroll
    for (int j=0;j<4;j++) acc[i][j] = 0.f;

  for (int ks = 0; ks < KTOT; ks += 64) {
    #pragma unroll
    for (int it = 0; it < 4; it++) {          // A: 64 rows x 64 k (transposed+swizzled)
      int idx = it*256 + tid;
      int row = idx >> 4, kq = idx & 15;
      float4 a4 = *(const float4*)(A + (size_t)(rb+row)*KTOT + ks + 4*kq);
      int rsw = row ^ (4*(kq & 7));
      As[4*kq+0][rsw] = a4.x; As[4*kq+1][rsw] = a4.y;
      As[4*kq+2][rsw] = a4.z; As[4*kq+3][rsw] = a4.w;
    }
    #pragma unroll
    for (int it = 0; it < 4; it++) {          // B: 64 k x 64 n
      int idx = it*256 + tid;
      int kk = idx >> 4, nq = idx & 15;
      *(float4*)(&Bs[kk][4*nq]) = *(const float4*)(Bw + (size_t)(ks+kk)*N + nb + 4*nq);
    }
    __syncthreads();
    #pragma unroll
    for (int k = 0; k < 64; k++) {
      float a[4], bv[4];
      *(float4*)a  = *(const float4*)&As[k][(4*ty) ^ (4*((k>>2)&7))];
      *(float4*)bv = *(const float4*)&Bs[k][4*tx];
      #pragma unroll
      for (int i=0;i<4;i++)
        #pragma unroll
        for (int j=0;j<4;j++)
          acc[i][j] = fmaf(a[i], bv[j], acc[i][j]);
    }
    __syncthreads();
  }

  #pragma unroll
  for (int i=0;i<4;i++) {
    int row = rb + 4*ty + i;
    float o[4];
    #pragma unroll
    for (int j=0;j<4;j++) {
      int col = nb + 4*tx + j;
      float v = acc[i][j];
      if (BIAS)  v += bias[col];
      if (GELU)  v = 0.5f * v * (1.f + erff(v * 0.70710678118f));
      if (RESID) v += Rsd[(size_t)row*N + col];
      o[j] = v;
    }
    if (XPOS) {
      if (nb < 256) {                       // rotate Q (0..127) / K (128..255)
        bool isK = (nb >= 128);
        const float* sn_t = tabs + (isK ? 65536 : 0);
        const float* cs_t = tabs + (isK ? 98304 : 32768);
        int s = row & (SEQL - 1);
        int cb = nb + 4*tx;
        int i0 = (cb & 31) >> 1;            // freq index of first pair
        float sn0 = sn_t[s*16 + i0],     cs0 = cs_t[s*16 + i0];
        float sn1 = sn_t[s*16 + i0 + 1], cs1 = cs_t[s*16 + i0 + 1];
        float x1 = o[0], x2 = o[1];
        o[0] = x1*cs0 - x2*sn0;  o[1] = x2*cs0 + x1*sn0;
        x1 = o[2]; x2 = o[3];
        o[2] = x1*cs1 - x2*sn1;  o[3] = x2*cs1 + x1*sn1;
      }
    }
    *(float4*)(C + (size_t)row*N + nb + 4*tx) = *(float4*)o;
  }
}

// ---------------------------------------------------------------------------
// Retention pass A: per (b,h,chunk) decayed KV summary
//   A_c[e,v] = sum_{t=0..63} gamma^(64-t) * K[c0+t,e] * V[c0+t,v]   (32x64)
// ---------------------------------------------------------------------------
__global__ __launch_bounds__(256) void ret_kv_kernel(
    const float* __restrict__ QKVG, float* __restrict__ Asum)
{
  int bh = blockIdx.x >> 5;       // b*4+h
  int c  = blockIdx.x & 31;
  int b = bh >> 2, h = bh & 3;
  float t0 = logf(1.f/32.f) + (float)h * (logf(1.f/512.f) - logf(1.f/32.f)) * (1.f/3.f);
  float gamma = 1.f - expf(t0);
  float lg = logf(gamma);

  __shared__ float Ks[64][36];
  __shared__ float Vs[64][68];
  __shared__ float wt[64];

  int tid = threadIdx.x;
  int c0 = c * 64;
  const float* base = QKVG + (size_t)(b * SEQL) * NCAT;

  #pragma unroll
  for (int it = 0; it < 2; it++) {
    int idx = it*256 + tid;
    int row = idx >> 3, eq = idx & 7;
    *(float4*)&Ks[row][4*eq] =
        *(const float4*)(base + (size_t)(c0+row)*NCAT + 128 + h*32 + 4*eq);
  }
  #pragma unroll
  for (int it = 0; it < 4; it++) {
    int idx = it*256 + tid;
    int row = idx >> 4, vq = idx & 15;
    *(float4*)&Vs[row][4*vq] =
        *(const float4*)(base + (size_t)(c0+row)*NCAT + 256 + h*64 + 4*vq);
  }
  if (tid < 64) wt[tid] = __expf(lg * (float)(64 - tid));
  __syncthreads();

  int e = tid >> 3, v8 = (tid & 7) * 8;
  float a0[4] = {0,0,0,0}, a1[4] = {0,0,0,0};
  #pragma unroll 4
  for (int t = 0; t < 64; t++) {
    float kw = Ks[t][e] * wt[t];
    float4 v0 = *(const float4*)&Vs[t][v8];
    float4 v1 = *(const float4*)&Vs[t][v8+4];
    a0[0] = fmaf(kw, v0.x, a0[0]); a0[1] = fmaf(kw, v0.y, a0[1]);
    a0[2] = fmaf(kw, v0.z, a0[2]); a0[3] = fmaf(kw, v0.w, a0[3]);
    a1[0] = fmaf(kw, v1.x, a1[0]); a1[1] = fmaf(kw, v1.y, a1[1]);
    a1[2] = fmaf(kw, v1.z, a1[2]); a1[3] = fmaf(kw, v1.w, a1[3]);
  }
  float* ob = Asum + ((size_t)(bh*NCHUNK + c))*2048 + e*64 + v8;
  *(float4*)ob     = *(float4*)a0;
  *(float4*)(ob+4) = *(float4*)a1;
}

// ---------------------------------------------------------------------------
// Retention pass C: per (b,h,chunk):
//   Sc = sum_{c'<c} g64^(c-1-c') A_{c'}          (cross-chunk state, 32x64)
//   Y  = (Q K^T (.) D_intra) V + diag(gamma^sl) Q Sc
// then fused GroupNorm(head) + SiLU(G) gate -> Gated
// ---------------------------------------------------------------------------
__global__ __launch_bounds__(256) void ret_out_kernel(
    const float* __restrict__ QKVG, const float* __restrict__ Asum,
    const float* __restrict__ gn_g, const float* __restrict__ gn_b,
    float* __restrict__ Gated)
{
  int bh = blockIdx.x >> 5;
  int c  = blockIdx.x & 31;
  int b = bh >> 2, h = bh & 3;
  float t0 = logf(1.f/32.f) + (float)h * (logf(1.f/512.f) - logf(1.f/32.f)) * (1.f/3.f);
  float gamma = 1.f - expf(t0);
  float lg = logf(gamma);
  float g64 = __expf(lg * 64.f);

  __shared__ float Qs[64][36];
  __shared__ float Ks[64][36];
  __shared__ float Vs[64][68];
  __shared__ float Ss[64][68];
  __shared__ float Sc[32][68];

  int tid = threadIdx.x, tx = tid & 15, ty = tid >> 4;
  int c0 = c * 64;
  const float* base = QKVG + (size_t)(b * SEQL) * NCAT;

  #pragma unroll
  for (int it = 0; it < 2; it++) {            // Q + K (swizzled) 64x32 each
    int idx = it*256 + tid;
    int row = idx >> 3, eq = idx & 7;
    *(float4*)&Qs[row][4*eq] =
        *(const float4*)(base + (size_t)(c0+row)*NCAT + h*32 + 4*eq);
    int esw = (4*eq) ^ (4*((row >> 2) & 7));
    *(float4*)&Ks[row][esw] =
        *(const float4*)(base + (size_t)(c0+row)*NCAT + 128 + h*32 + 4*eq);
  }
  #pragma unroll
  for (int it = 0; it < 4; it++) {            // V 64x64
    int idx = it*256 + tid;
    int row = idx >> 4, vq = idx & 15;
    *(float4*)&Vs[row][4*vq] =
        *(const float4*)(base + (size_t)(c0+row)*NCAT + 256 + h*64 + 4*vq);
  }

  {                                           // cross-chunk state combine
    int e = tid >> 3, v8 = (tid & 7) * 8;
    float s0[4] = {0,0,0,0}, s1[4] = {0,0,0,0};
    float w = 1.f;
    const float* ab = Asum + ((size_t)bh*NCHUNK)*2048 + e*64 + v8;
    for (int cp = c-1; cp >= 0; --cp) {
      const float* ap = ab + (size_t)cp*2048;
      float4 x0 = *(const float4*)ap;
      float4 x1 = *(const float4*)(ap+4);
      s0[0] = fmaf(w, x0.x, s0[0]); s0[1] = fmaf(w, x0.y, s0[1]);
      s0[2] = fmaf(w, x0.z, s0[2]); s0[3] = fmaf(w, x0.w, s0[3]);
      s1[0] = fmaf(w, x1.x, s1[0]); s1[1] = fmaf(w, x1.y, s1[1]);
      s1[2] = fmaf(w, x1.z, s1[2]); s1[3] = fmaf(w, x1.w, s1[3]);
      w *= g64;
    }
    *(float4*)&Sc[e][v8]   = *(float4*)s0;
    *(float4*)&Sc[e][v8+4] = *(float4*)s1;
  }
  __syncthreads();

  // intra-chunk S = Q K^T (.) decay  -> Ss
  float sacc[4][4];
  #pragma unroll
  for (int i=0;i<4;i++)
    #pragma unroll
    for (int j=0;j<4;j++) sacc[i][j] = 0.f;
  #pragma unroll
  for (int e = 0; e < 32; e += 4) {
    float qv[4][4], kv[4][4];
    #pragma unroll
    for (int i=0;i<4;i++)
      *(float4*)qv[i] = *(const float4*)&Qs[4*ty+i][e];
    int esw = e ^ (4*(tx & 7));
    #pragma unroll
    for (int j=0;j<4;j++)
      *(float4*)kv[j] = *(const float4*)&Ks[4*tx+j][esw];
    #pragma unroll
    for (int i=0;i<4;i++)
      #pragma unroll
      for (int j=0;j<4;j++)
        sacc[i][j] = fmaf(qv[i][0], kv[j][0],
                     fmaf(qv[i][1], kv[j][1],
                     fmaf(qv[i][2], kv[j][2],
                     fmaf(qv[i][3], kv[j][3], sacc[i][j]))));
  }
  #pragma unroll
  for (int i=0;i<4;i++) {                     // decay mask, float4 store
    int sl = 4*ty + i;
    float o4[4];
    #pragma unroll
    for (int j=0;j<4;j++) {
      int dr = sl - (4*tx + j);
      float w = (dr >= 0) ? __expf(lg * (float)dr) : 0.f;
      o4[j] = sacc[i][j] * w;
    }
    *(float4*)&Ss[sl][4*tx] = *(float4*)o4;
  }

  // cross term: acc = diag(gamma^sl) * (Q @ Sc)
  float acc[4][4];
  #pragma unroll
  for (int i=0;i<4;i++)
    #pragma unroll
    for (int j=0;j<4;j++) acc[i][j] = 0.f;
  #pragma unroll
  for (int e = 0; e < 32; e += 4) {
    float qv[4][4], sv[4][4];
    #pragma unroll
    for (int i=0;i<4;i++)
      *(float4*)qv[i] = *(const float4*)&Qs[4*ty+i][e];
    #pragma unroll
    for (int m=0;m<4;m++)
      *(float4*)sv[m] = *(const float4*)&Sc[e+m][4*tx];
    #pragma unroll
    for (int i=0;i<4;i++)
      #pragma unroll
      for (int j=0;j<4;j++)
        acc[i][j] = fmaf(qv[i][0], sv[0][j],
                    fmaf(qv[i][1], sv[1][j],
                    fmaf(qv[i][2], sv[2][j],
                    fmaf(qv[i][3], sv[3][j], acc[i][j]))));
  }
  #pragma unroll
  for (int i=0;i<4;i++) {
    float gr = __expf(lg * (float)(4*ty + i));
    #pragma unroll
    for (int j=0;j<4;j++) acc[i][j] *= gr;
  }
  __syncthreads();

  // Y += Ss @ V
  #pragma unroll
  for (int t = 0; t < 64; t += 4) {
    float sv[4][4], vv[4][4];
    #pragma unroll
    for (int i=0;i<4;i++)
      *(float4*)sv[i] = *(const float4*)&Ss[4*ty+i][t];
    #pragma unroll
    for (int m=0;m<4;m++)
      *(float4*)vv[m] = *(const float4*)&Vs[t+m][4*tx];
    #pragma unroll
    for (int i=0;i<4;i++)
      #pragma unroll
      for (int j=0;j<4;j++)
        acc[i][j] = fmaf(sv[i][0], vv[0][j],
                    fmaf(sv[i][1], vv[1][j],
                    fmaf(sv[i][2], vv[2][j],
                    fmaf(sv[i][3], vv[3][j], acc[i][j]))));
  }

  // fused GroupNorm (per head, 64 cols spread over 16 lanes) + SiLU gate
  #pragma unroll
  for (int i=0;i<4;i++) {
    float s1 = acc[i][0] + acc[i][1] + acc[i][2] + acc[i][3];
    #pragma unroll
    for (int o = 8; o; o >>= 1) s1 += __shfl_xor(s1, o);
    float mu = s1 * (1.f/64.f);
    float q = 0.f;
    #pragma unroll
    for (int j=0;j<4;j++) { float d = acc[i][j] - mu; q += d*d; }
    #pragma unroll
    for (int o = 8; o; o >>= 1) q += __shfl_xor(q, o);
    float rs = rsqrtf(q * (1.f/64.f) + 1e-5f);
    int row = b*SEQL + c0 + 4*ty + i;
    float4 g4 = *(const float4*)(QKVG + (size_t)row*NCAT + 512 + h*64 + 4*tx);
    float gv[4] = {g4.x, g4.y, g4.z, g4.w};
    float o4[4];
    #pragma unroll
    for (int j=0;j<4;j++) {
      int col = h*64 + 4*tx + j;
      float yn = (acc[i][j] - mu) * rs * gn_g[col] + gn_b[col];
      float g = gv[j];
      float sig = 1.f / (1.f + __expf(-g));
      o4[j] = g * sig * yn;
    }
    *(float4*)(Gated + (size_t)row*VD + h*64 + 4*tx) = *(float4*)o4;
  }
}

// ---------------------------------------------------------------------------
extern "C" void kernel_launch(void* const* d_in, const int* in_sizes, int n_in,
                              void* d_out, int out_size, void* d_ws, size_t ws_size,
                              hipStream_t stream)
{
  (void)in_sizes; (void)n_in; (void)out_size; (void)ws_size;
  const float* x_in  = (const float*)d_in[0];
  const float* ln1_g = (const float*)d_in[1];
  const float* ln1_b = (const float*)d_in[2];
  const float* ln2_g = (const float*)d_in[3];
  const float* ln2_b = (const float*)d_in[4];
  const float* WQ    = (const float*)d_in[5];
  const float* WK    = (const float*)d_in[6];
  const float* WV    = (const float*)d_in[7];
  const float* WG    = (const float*)d_in[8];
  const float* WO    = (const float*)d_in[9];
  const float* gn_g  = (const float*)d_in[10];
  const float* gn_b  = (const float*)d_in[11];
  const float* w1    = (const float*)d_in[12];
  const float* b1    = (const float*)d_in[13];
  const float* w2    = (const float*)d_in[14];
  const float* b2    = (const float*)d_in[15];
  float* out = (float*)d_out;
  float* ws  = (float*)d_ws;

  float* Wcat = ws;                       // 196608
  float* tabs = Wcat + 196608;            // 131072
  float* Hbuf = tabs + 131072;            // 524288 (LN1 out; reused for LN2 out)
  float* QKVG = Hbuf + 524288;            // 3145728
  float* Asum = QKVG + 3145728;           // 524288
  float* Gt   = Asum + 524288;            // 1048576
  float* Yres = Gt   + 1048576;           // 524288
  float* Mid  = Yres + 524288;            // 1048576

  pack_w_kernel<<<768, 256, 0, stream>>>(WQ, WK, WV, WG, Wcat);
  xpos_tables_kernel<<<128, 256, 0, stream>>>(tabs);

  for (int l = 0; l < NLAYERS; l++) {
    const float* xl = (l == 0) ? x_in : out;
    ln_rows_kernel<<<MROWS/4, 256, 0, stream>>>(xl, ln1_g + l*HID, ln1_b + l*HID, Hbuf);
    gemm64<128,false,false,false,true><<<dim3(MROWS/64, NCAT/64), 256, 0, stream>>>(
        Hbuf, Wcat + l*HID*NCAT, nullptr, nullptr, tabs, QKVG, NCAT);
    ret_kv_kernel<<<256, 256, 0, stream>>>(QKVG, Asum);
    ret_out_kernel<<<256, 256, 0, stream>>>(QKVG, Asum, gn_g + l*VD, gn_b + l*VD, Gt);
    gemm64<256,false,true,false,false><<<dim3(MROWS/64, HID/64), 256, 0, stream>>>(
        Gt, WO + l*VD*HID, nullptr, xl, nullptr, Yres, HID);
    ln_rows_kernel<<<MROWS/4, 256, 0, stream>>>(Yres, ln2_g + l*HID, ln2_b + l*HID, Hbuf);
    gemm64<128,true,false,true,false><<<dim3(MROWS/64, FFND/64), 256, 0, stream>>>(
        Hbuf, w1 + l*HID*FFND, b1 + l*FFND, nullptr, nullptr, Mid, FFND);
    gemm64<256,true,true,false,false><<<dim3(MROWS/64, HID/64), 256, 0, stream>>>(
        Mid, w2 + l*FFND*HID, b2 + l*HID, Yres, nullptr, out, HID);
  }
}